// Round 1
// baseline (902.538 us; speedup 1.0000x reference)
//
#include <hip/hip_runtime.h>
#include <hip/hip_fp16.h>

// Elman RNN, restructured:
//   prep:   W23 = W2@W3, b23 = b2@W3+b3; pack W1x/W1h as f16 pairs (k-pairs, col-major-friendly)
//   phase1: premb[v][j] = sum_k emb[v][k]*W1[k][j] + b1[j]   (vocab rows, f16 out)
//   phase2: per-batch WG (128 WGs): h = sigmoid(premb[x[b][t]] + W1h^T h)  (512 seq steps)
//           W1h resident in VGPRs (f16 pairs), h broadcast via v_readlane, v_dot2_f32_f16
//   phase3: out[b][t][c] = h[b][t]@W23[:,c] + b23[c]

typedef _Float16 half2v __attribute__((ext_vector_type(2)));

#define NVOCAB 32000
#define NB 128
#define NT 512

// workspace byte offsets
#define OFF_PREMB 0ull                 // f16 [32000][300]        = 19,200,000
#define OFF_HALL  19200000ull          // u32 [65536][160]        = 41,943,040
#define OFF_PWX   61143040ull          // u32 [150][300]          =    180,000
#define OFF_PWH   61323040ull          // u32 [150][300]          =    180,000
#define OFF_W23   61503040ull          // f32 [300][2]            =      2,400
#define OFF_B23   61505440ull          // f32 [2]

__device__ __forceinline__ float dot2f(unsigned int w, unsigned int h, float acc) {
#if __has_builtin(__builtin_amdgcn_fdot2)
  return __builtin_amdgcn_fdot2(__builtin_bit_cast(half2v, w),
                                __builtin_bit_cast(half2v, h), acc, false);
#else
  half2v wv = __builtin_bit_cast(half2v, w), hv = __builtin_bit_cast(half2v, h);
  return acc + (float)wv.x * (float)hv.x + (float)wv.y * (float)hv.y;
#endif
}

// 150-pair dot: this thread's half (hhs selects pairs [0,75) or [75,150)).
// h pairs replicated per-wave in vh0/vh1/vh2 (lane l of vhq holds pair 64q+l).
__device__ __forceinline__ float dot150(int hhs, unsigned int vh0, unsigned int vh1,
                                        unsigned int vh2, const unsigned int (&pw)[75]) {
  float accA = 0.f, accB = 0.f;
  if (hhs == 0) {
#pragma unroll
    for (int i = 0; i < 75; ++i) {
      const int p = i;  // pairs 0..74
      unsigned int hp = (unsigned int)__builtin_amdgcn_readlane((int)(p < 64 ? vh0 : vh1), p & 63);
      if (i & 1) accB = dot2f(pw[i], hp, accB);
      else       accA = dot2f(pw[i], hp, accA);
    }
  } else {
#pragma unroll
    for (int i = 0; i < 75; ++i) {
      const int p = 75 + i;  // pairs 75..149
      unsigned int hp = (unsigned int)__builtin_amdgcn_readlane((int)(p < 128 ? vh1 : vh2), p & 63);
      if (i & 1) accB = dot2f(pw[i], hp, accB);
      else       accA = dot2f(pw[i], hp, accA);
    }
  }
  return accA + accB;
}

__global__ __launch_bounds__(256) void rnn_prep(const float* __restrict__ W1,
                                                const float* __restrict__ W2,
                                                const float* __restrict__ b2,
                                                const float* __restrict__ W3,
                                                const float* __restrict__ b3,
                                                unsigned char* __restrict__ ws) {
  unsigned int tid = blockIdx.x * 256 + threadIdx.x;
  unsigned int* pwx = (unsigned int*)(ws + OFF_PWX);
  unsigned int* pwh = (unsigned int*)(ws + OFF_PWH);
  float* w23 = (float*)(ws + OFF_W23);
  float* b23 = (float*)(ws + OFF_B23);
  if (tid < 90000u) {
    int part = tid / 45000;           // 0 = W1x (k<300), 1 = W1h (k>=300)
    int r = tid % 45000;
    int i = r / 300, j = r % 300;     // pair i, column j
    int k0 = part * 300 + 2 * i;
    unsigned int lo = __half_as_ushort(__float2half(W1[(size_t)k0 * 300 + j]));
    unsigned int hi = __half_as_ushort(__float2half(W1[(size_t)(k0 + 1) * 300 + j]));
    (part ? pwh : pwx)[i * 300 + j] = (hi << 16) | lo;
  } else if (tid < 90300u) {
    int j = tid - 90000;
    float s0 = 0.f, s1 = 0.f;
    for (int k = 0; k < 300; ++k) {
      float w = W2[j * 300 + k];
      s0 += w * W3[k * 2 + 0];
      s1 += w * W3[k * 2 + 1];
    }
    w23[j * 2 + 0] = s0;
    w23[j * 2 + 1] = s1;
  } else if (tid == 90300u) {
    float s0 = b3[0], s1 = b3[1];
    for (int k = 0; k < 300; ++k) {
      s0 += b2[k] * W3[k * 2 + 0];
      s1 += b2[k] * W3[k * 2 + 1];
    }
    b23[0] = s0; b23[1] = s1;
  }
}

__global__ __launch_bounds__(640) void rnn_phase1(const float* __restrict__ emb,
                                                  const float* __restrict__ b1,
                                                  unsigned char* __restrict__ ws) {
  __shared__ unsigned int hpk[192];
  __shared__ float redbuf[320];
  const unsigned int* pwx = (const unsigned int*)(ws + OFF_PWX);
  unsigned short* premb = (unsigned short*)(ws + OFF_PREMB);
  const int tid = threadIdx.x;
  const int hh = (tid >= 320) ? 1 : 0;
  const int hhs = __builtin_amdgcn_readfirstlane(hh);  // wave-uniform scalar branch
  const int col = hh ? tid - 320 : tid;
  const int lane = tid & 63;
  unsigned int pw[75];
  if (col < 300) {
#pragma unroll
    for (int i = 0; i < 75; ++i) pw[i] = pwx[(hhs * 75 + i) * 300 + col];
  }
  float breg = (hhs == 0 && col < 300) ? b1[col] : 0.f;
  if (tid >= 150 && tid < 192) hpk[tid] = 0u;
  for (int v = blockIdx.x; v < NVOCAB; v += gridDim.x) {
    __syncthreads();  // previous iteration's hpk readers done
    if (tid < 150) {
      float2 e = *(const float2*)(emb + (size_t)v * 300 + 2 * tid);
      unsigned int lo = __half_as_ushort(__float2half(e.x));
      unsigned int hi = __half_as_ushort(__float2half(e.y));
      hpk[tid] = (hi << 16) | lo;
    }
    __syncthreads();
    unsigned int vh0 = hpk[lane], vh1 = hpk[64 + lane], vh2 = hpk[128 + lane];
    float acc = dot150(hhs, vh0, vh1, vh2, pw);
    if (hhs != 0) { if (col < 300) redbuf[col] = acc; }
    __syncthreads();
    if (hhs == 0 && col < 300) {
      float a = acc + redbuf[col] + breg;
      premb[(size_t)v * 300 + col] = __half_as_ushort(__float2half(a));
    }
  }
}

__global__ __launch_bounds__(640) void rnn_phase2(const int* __restrict__ x,
                                                  unsigned char* __restrict__ ws) {
  __shared__ unsigned int hpk[192];
  __shared__ float redbuf[320];
  __shared__ int xl[NT];
  const unsigned int* pwh = (const unsigned int*)(ws + OFF_PWH);
  const unsigned short* premb = (const unsigned short*)(ws + OFF_PREMB);
  unsigned int* hall = (unsigned int*)(ws + OFF_HALL);
  const int tid = threadIdx.x;
  const int b = blockIdx.x;
  const int hh = (tid >= 320) ? 1 : 0;
  const int hhs = __builtin_amdgcn_readfirstlane(hh);
  const int col = hh ? tid - 320 : tid;
  const int lane = tid & 63;
  unsigned int pw[75];
  if (col < 300) {
#pragma unroll
    for (int i = 0; i < 75; ++i) pw[i] = pwh[(hhs * 75 + i) * 300 + col];
  }
  for (int i = tid; i < NT; i += 640) xl[i] = x[b * NT + i];
  if (tid >= 150 && tid < 192) hpk[tid] = 0u;
  unsigned int vh0 = 0u, vh1 = 0u, vh2 = 0u;  // h0 = zeros
  __syncthreads();
  for (int t = 0; t < NT; ++t) {
    // prefetch this step's premb row (latency hides under the dot phase)
    float pnext = 0.f;
    if (hhs == 0 && col < 300) {
      int v = xl[t];
      pnext = __half2float(__ushort_as_half(premb[(size_t)v * 300 + col]));
    }
    float acc = dot150(hhs, vh0, vh1, vh2, pw);
    if (hhs != 0) { if (col < 300) redbuf[col] = acc; }
    __syncthreads();
    if (hhs == 0 && col < 300) {
      float a = acc + redbuf[col] + pnext;
      float h = 1.0f / (1.0f + __expf(-a));
      ((unsigned short*)hpk)[col] = __half_as_ushort(__float2half(h));
    }
    __syncthreads();
    vh0 = hpk[lane]; vh1 = hpk[64 + lane]; vh2 = hpk[128 + lane];
    if (tid < 150) hall[(size_t)(b * NT + t) * 160 + tid] = hpk[tid];
  }
}

__global__ __launch_bounds__(256) void rnn_phase3(const unsigned char* __restrict__ ws,
                                                  float* __restrict__ out) {
  int gw = (blockIdx.x * 256 + threadIdx.x) >> 6;  // one wave per (b,t) row, 65536 total
  int lane = threadIdx.x & 63;
  const unsigned int* hall = (const unsigned int*)(ws + OFF_HALL);
  const float* w23 = (const float*)(ws + OFF_W23);
  const float* b23 = (const float*)(ws + OFF_B23);
  const unsigned int* hr = hall + (size_t)gw * 160u;
  unsigned int h0 = hr[lane];
  unsigned int h1 = hr[64 + lane];
  unsigned int h2 = (lane < 22) ? hr[128 + lane] : 0u;
  float s0 = 0.f, s1 = 0.f;
  {
    int p = lane;
    half2v hv = __builtin_bit_cast(half2v, h0);
    float e0 = (float)hv.x, e1 = (float)hv.y;
    s0 += e0 * w23[(2 * p) * 2 + 0] + e1 * w23[(2 * p + 1) * 2 + 0];
    s1 += e0 * w23[(2 * p) * 2 + 1] + e1 * w23[(2 * p + 1) * 2 + 1];
  }
  {
    int p = 64 + lane;
    half2v hv = __builtin_bit_cast(half2v, h1);
    float e0 = (float)hv.x, e1 = (float)hv.y;
    s0 += e0 * w23[(2 * p) * 2 + 0] + e1 * w23[(2 * p + 1) * 2 + 0];
    s1 += e0 * w23[(2 * p) * 2 + 1] + e1 * w23[(2 * p + 1) * 2 + 1];
  }
  if (lane < 22) {
    int p = 128 + lane;
    half2v hv = __builtin_bit_cast(half2v, h2);
    float e0 = (float)hv.x, e1 = (float)hv.y;
    s0 += e0 * w23[(2 * p) * 2 + 0] + e1 * w23[(2 * p + 1) * 2 + 0];
    s1 += e0 * w23[(2 * p) * 2 + 1] + e1 * w23[(2 * p + 1) * 2 + 1];
  }
  for (int m = 32; m; m >>= 1) {
    s0 += __shfl_xor(s0, m, 64);
    s1 += __shfl_xor(s1, m, 64);
  }
  if (lane == 0) {
    float2 o;
    o.x = s0 + b23[0];
    o.y = s1 + b23[1];
    *(float2*)(out + (size_t)gw * 2) = o;
  }
}

extern "C" void kernel_launch(void* const* d_in, const int* in_sizes, int n_in,
                              void* d_out, int out_size, void* d_ws, size_t ws_size,
                              hipStream_t stream) {
  const int* x = (const int*)d_in[0];
  const float* emb = (const float*)d_in[1];
  const float* W1 = (const float*)d_in[2];
  const float* b1 = (const float*)d_in[3];
  const float* W2 = (const float*)d_in[4];
  const float* b2 = (const float*)d_in[5];
  const float* W3 = (const float*)d_in[6];
  const float* b3 = (const float*)d_in[7];
  unsigned char* ws = (unsigned char*)d_ws;
  float* out = (float*)d_out;

  hipLaunchKernelGGL(rnn_prep, dim3(354), dim3(256), 0, stream, W1, W2, b2, W3, b3, ws);
  hipLaunchKernelGGL(rnn_phase1, dim3(256), dim3(640), 0, stream, emb, b1, ws);
  hipLaunchKernelGGL(rnn_phase2, dim3(NB), dim3(640), 0, stream, x, ws);
  hipLaunchKernelGGL(rnn_phase3, dim3(16384), dim3(256), 0, stream, ws, out);
}